// Round 2
// baseline (490.581 us; speedup 1.0000x reference)
//
#include <hip/hip_runtime.h>
#include <hip/hip_bf16.h>
#include <math.h>

typedef _Float16 f16;
typedef _Float16 f16x8 __attribute__((ext_vector_type(8)));
typedef _Float16 f16x4 __attribute__((ext_vector_type(4)));
typedef float f32x4 __attribute__((ext_vector_type(4)));

#define MFMA(a, b, c) __builtin_amdgcn_mfma_f32_16x16x32_f16((a), (b), (c), 0, 0, 0)

constexpr int Dd = 64;    // latent dims
constexpr int Hh = 128;   // hidden
constexpr int Nn = 4096;  // B*length
constexpr int NT = 32;    // samples per block
constexpr float SLP = 0.2f;
constexpr float INV2K = 1.0f / 2048.0f;

// XOR swizzle: row-major [r][128] f16, 8-elem chunks, chunk ^= r&15.
// b128 frag reads and b64 epilogue writes both land 2-way max per bank (free).
__device__ __forceinline__ int swz(int r, int c) {
  return (r << 7) + ((((c >> 3) ^ (r & 15)) << 3) | (c & 7));
}

// Split fp32 into hi + lo/2048 fp16 pair (~22-bit mantissa total).
struct HL { f16 h, l; };
__device__ __forceinline__ HL split(float v) {
  HL r;
  r.h = (f16)v;
  r.l = (f16)((v - (float)r.h) * 2048.0f);
  return r;
}

// Stage 64x128 f32 row-major weights into hi/lo swizzled LDS.
__device__ __forceinline__ void stage_wf(f16* WH, f16* WL,
                                         const float* __restrict__ g, int tid) {
  for (int i = tid; i < 2048; i += 256) {
    int h = i >> 5, k4 = (i & 31) << 2;
    float4 v = ((const float4*)g)[i];
    HL a = split(v.x), b = split(v.y), c = split(v.z), e = split(v.w);
    f16x4 hv = {a.h, b.h, c.h, e.h};
    f16x4 lv = {a.l, b.l, c.l, e.l};
    int o = swz(h, k4);
    *(f16x4*)&WH[o] = hv;
    *(f16x4*)&WL[o] = lv;
  }
}

// One W-half (64 h-rows) of a mid layer: [A;D] x W^T, split-fp16 3-product.
// Operand order mfma(W_frag, act_frag): output rows (quad*4+j) index h,
// cols (lane&15) index n -> epilogue writes 4 consecutive h per lane (b64).
__device__ __forceinline__ void mid_mfma_half(
    const f16* AH, const f16* AL, const f16* DH, const f16* DL,
    const f16* WH, const f16* WL, int nt, int wq, int l15, int quad,
    f32x4* aP, f32x4* aS, f32x4* dP, f32x4* dS) {
#pragma unroll
  for (int kc = 0; kc < 4; kc++) {
    int ko = kc * 32 + quad * 8;
    int ra = nt * 16 + l15;
    f16x8 xh = *(const f16x8*)&AH[swz(ra, ko)];
    f16x8 xl = *(const f16x8*)&AL[swz(ra, ko)];
    f16x8 yh = *(const f16x8*)&DH[swz(ra, ko)];
    f16x8 yl = *(const f16x8*)&DL[swz(ra, ko)];
#pragma unroll
    for (int c2 = 0; c2 < 2; c2++) {
      int hr = (2 * wq + c2) * 16 + l15;
      f16x8 wh = *(const f16x8*)&WH[swz(hr, ko)];
      f16x8 wl = *(const f16x8*)&WL[swz(hr, ko)];
      aP[c2] = MFMA(wh, xh, aP[c2]);
      aS[c2] = MFMA(wl, xh, aS[c2]);
      aS[c2] = MFMA(wh, xl, aS[c2]);
      dP[c2] = MFMA(wh, yh, dP[c2]);
      dS[c2] = MFMA(wl, yh, dS[c2]);
      dS[c2] = MFMA(wh, yl, dS[c2]);
    }
  }
}

__global__ __launch_bounds__(256, 2)
void np_prior_kernel(const float* __restrict__ x,
                     const float* __restrict__ W1, const float* __restrict__ b1,
                     const float* __restrict__ W2, const float* __restrict__ b2,
                     const float* __restrict__ W3, const float* __restrict__ b3,
                     const float* __restrict__ W4, const float* __restrict__ b4,
                     float* __restrict__ out_res, float* __restrict__ out_log) {
  __shared__ float4 smem[4096];  // 64 KB exactly
  f16* AH = (f16*)smem;          // a-chain hi  [32][128]  8 KB
  f16* AL = AH + NT * 128;       // a-chain lo              8 KB
  f16* DH = AL + NT * 128;       // d-chain hi              8 KB
  f16* DL = DH + NT * 128;       // d-chain lo              8 KB
  f16* WHp = (f16*)((char*)smem + 32768);  // W half hi [64][128] 16 KB
  f16* WLp = WHp + 64 * 128;               // W half lo           16 KB
  float* A3F = (float*)smem;                  // L3 out a3 f32 [32][128] (overlay)
  float* D3F = (float*)((char*)smem + 16384); // L3 out d3 f32 (overlay)

  const int tid = threadIdx.x, d = blockIdx.y, n0 = blockIdx.x * NT;
  const int lane = tid & 63, wv = tid >> 6, l15 = lane & 15, quad = lane >> 4;
  const int nt = wv & 1;   // n-tile (16 samples)
  const int wq = wv >> 1;  // h-tile pair within a W-half

  const float* W1d = W1 + d * Hh * 65;
  const float* b1d = b1 + d * Hh;
  const f32x4 zero = {0.f, 0.f, 0.f, 0.f};

  // ---- stage x_lags (k<64) hi/lo
  for (int i = tid; i < NT * 16; i += 256) {
    int n = i >> 4, k4 = (i & 15) << 2;
    int ng = n0 + n, bb = ng >> 8, tt = ng & 255;
    float4 v = *(const float4*)&x[(bb * 257 + tt) * 64 + k4];
    HL a = split(v.x), b = split(v.y), c = split(v.z), e = split(v.w);
    f16x4 hv = {a.h, b.h, c.h, e.h};
    f16x4 lv = {a.l, b.l, c.l, e.l};
    int o = swz(n, k4);
    *(f16x4*)&AH[o] = hv;
    *(f16x4*)&AL[o] = lv;
  }
  // x_t for this lane's sample (L1 epilogue rank-1 term), fp32 exact
  float xtv;
  {
    int ng = n0 + nt * 16 + l15, bb = ng >> 8, tt = ng & 255;
    xtv = x[(bb * 257 + tt + 1) * 64 + d];
  }
  // ---- stage W1 half 0 (h 0..63, k<64; stride-65 source)
  for (int i = tid; i < 64 * 64; i += 256) {
    int h = i >> 6, k = i & 63;
    HL s = split(W1d[h * 65 + k]);
    int o = swz(h, k);
    WHp[o] = s.h;
    WLp[o] = s.l;
  }
  __syncthreads();

  // ---- Layer 1 (K=64, A-chain only)
  f32x4 l1P[2][2], l1S[2][2];
  for (int hf = 0; hf < 2; hf++) {
    if (hf == 1) {
      __syncthreads();  // half-0 MFMA reads done before W overwrite
      for (int i = tid; i < 64 * 64; i += 256) {
        int h = i >> 6, k = i & 63;
        HL s = split(W1d[(64 + h) * 65 + k]);
        int o = swz(h, k);
        WHp[o] = s.h;
        WLp[o] = s.l;
      }
      __syncthreads();
    }
    l1P[hf][0] = zero; l1P[hf][1] = zero;
    l1S[hf][0] = zero; l1S[hf][1] = zero;
#pragma unroll
    for (int kc = 0; kc < 2; kc++) {
      int ko = kc * 32 + quad * 8;
      f16x8 xh = *(const f16x8*)&AH[swz(nt * 16 + l15, ko)];
      f16x8 xl = *(const f16x8*)&AL[swz(nt * 16 + l15, ko)];
#pragma unroll
      for (int c2 = 0; c2 < 2; c2++) {
        int hr = (2 * wq + c2) * 16 + l15;
        f16x8 wh = *(const f16x8*)&WHp[swz(hr, ko)];
        f16x8 wl = *(const f16x8*)&WLp[swz(hr, ko)];
        l1P[hf][c2] = MFMA(wh, xh, l1P[hf][c2]);
        l1S[hf][c2] = MFMA(wl, xh, l1S[hf][c2]);
        l1S[hf][c2] = MFMA(wh, xl, l1S[hf][c2]);
      }
    }
  }
  __syncthreads();  // all L1 MFMA done before act overwrite

  // ---- L1 epilogue: a1 = leaky(p1), d1 = s1 * W1[:,64]
  {
    int n = nt * 16 + l15;
#pragma unroll
    for (int hf = 0; hf < 2; hf++)
#pragma unroll
      for (int c2 = 0; c2 < 2; c2++) {
        int hb = hf * 64 + (2 * wq + c2) * 16 + quad * 4;
        f16x4 ah, al, dh, dl;
#pragma unroll
        for (int j = 0; j < 4; j++) {
          int h = hb + j;
          float w1l = W1d[h * 65 + 64];
          float p = l1P[hf][c2][j] + l1S[hf][c2][j] * INV2K + xtv * w1l + b1d[h];
          float s = p > 0.f ? 1.f : SLP;
          HL av = split(p * s), dv = split(s * w1l);
          ah[j] = av.h; al[j] = av.l;
          dh[j] = dv.h; dl[j] = dv.l;
        }
        int o = swz(n, hb);
        *(f16x4*)&AH[o] = ah; *(f16x4*)&AL[o] = al;
        *(f16x4*)&DH[o] = dh; *(f16x4*)&DL[o] = dl;
      }
  }
  stage_wf(WHp, WLp, W2 + d * Hh * Hh, tid);  // W2 half0, concurrent w/ epilogue
  __syncthreads();

  // ---- Layer 2
  f32x4 aP[2][2], aS[2][2], dP[2][2], dS[2][2];
  for (int hf = 0; hf < 2; hf++) {
    if (hf == 1) {
      __syncthreads();
      stage_wf(WHp, WLp, W2 + d * Hh * Hh + 64 * 128, tid);
      __syncthreads();
    }
    aP[hf][0] = zero; aP[hf][1] = zero; aS[hf][0] = zero; aS[hf][1] = zero;
    dP[hf][0] = zero; dP[hf][1] = zero; dS[hf][0] = zero; dS[hf][1] = zero;
    mid_mfma_half(AH, AL, DH, DL, WHp, WLp, nt, wq, l15, quad,
                  aP[hf], aS[hf], dP[hf], dS[hf]);
  }
  __syncthreads();

  // ---- L2 epilogue
  {
    const float* b2d = b2 + d * Hh;
    int n = nt * 16 + l15;
#pragma unroll
    for (int hf = 0; hf < 2; hf++)
#pragma unroll
      for (int c2 = 0; c2 < 2; c2++) {
        int hb = hf * 64 + (2 * wq + c2) * 16 + quad * 4;
        f16x4 ah, al, dh, dl;
#pragma unroll
        for (int j = 0; j < 4; j++) {
          int h = hb + j;
          float p = aP[hf][c2][j] + aS[hf][c2][j] * INV2K + b2d[h];
          float s = p > 0.f ? 1.f : SLP;
          float dd = s * (dP[hf][c2][j] + dS[hf][c2][j] * INV2K);
          HL av = split(p * s), dv = split(dd);
          ah[j] = av.h; al[j] = av.l;
          dh[j] = dv.h; dl[j] = dv.l;
        }
        int o = swz(n, hb);
        *(f16x4*)&AH[o] = ah; *(f16x4*)&AL[o] = al;
        *(f16x4*)&DH[o] = dh; *(f16x4*)&DL[o] = dl;
      }
  }
  stage_wf(WHp, WLp, W3 + d * Hh * Hh, tid);  // W3 half0
  __syncthreads();

  // ---- Layer 3
  for (int hf = 0; hf < 2; hf++) {
    if (hf == 1) {
      __syncthreads();
      stage_wf(WHp, WLp, W3 + d * Hh * Hh + 64 * 128, tid);
      __syncthreads();
    }
    aP[hf][0] = zero; aP[hf][1] = zero; aS[hf][0] = zero; aS[hf][1] = zero;
    dP[hf][0] = zero; dP[hf][1] = zero; dS[hf][0] = zero; dS[hf][1] = zero;
    mid_mfma_half(AH, AL, DH, DL, WHp, WLp, nt, wq, l15, quad,
                  aP[hf], aS[hf], dP[hf], dS[hf]);
  }
  __syncthreads();  // all act reads done; safe to overlay f32

  // ---- L3 epilogue: store a3, d3 as fp32 for the VALU L4
  {
    const float* b3d = b3 + d * Hh;
    int n = nt * 16 + l15;
#pragma unroll
    for (int hf = 0; hf < 2; hf++)
#pragma unroll
      for (int c2 = 0; c2 < 2; c2++) {
        int hb = hf * 64 + (2 * wq + c2) * 16 + quad * 4;
        float4 pa, pd;
        float tmpa[4], tmpd[4];
#pragma unroll
        for (int j = 0; j < 4; j++) {
          int h = hb + j;
          float p = aP[hf][c2][j] + aS[hf][c2][j] * INV2K + b3d[h];
          float s = p > 0.f ? 1.f : SLP;
          tmpa[j] = p * s;
          tmpd[j] = s * (dP[hf][c2][j] + dS[hf][c2][j] * INV2K);
        }
        pa.x = tmpa[0]; pa.y = tmpa[1]; pa.z = tmpa[2]; pa.w = tmpa[3];
        pd.x = tmpd[0]; pd.y = tmpd[1]; pd.z = tmpd[2]; pd.w = tmpd[3];
        *(float4*)&A3F[n * 128 + hb] = pa;
        *(float4*)&D3F[n * 128 + hb] = pd;
      }
  }
  __syncthreads();

  // ---- Layer 4: fp32 VALU dot, 8 threads per sample
  {
    int n = tid >> 3, oct = tid & 7;
    const float* w4d = W4 + d * Hh;
    float sr = 0.f, sd = 0.f;
#pragma unroll
    for (int i = 0; i < 4; i++) {
      int c = oct * 16 + i * 4;
      float4 va = *(const float4*)&A3F[n * 128 + c];
      float4 vd = *(const float4*)&D3F[n * 128 + c];
      float4 w = *(const float4*)&w4d[c];
      sr += va.x * w.x + va.y * w.y + va.z * w.z + va.w * w.w;
      sd += vd.x * w.x + vd.y * w.y + vd.z * w.z + vd.w * w.w;
    }
    sr += __shfl_xor(sr, 1); sr += __shfl_xor(sr, 2); sr += __shfl_xor(sr, 4);
    sd += __shfl_xor(sd, 1); sd += __shfl_xor(sd, 2); sd += __shfl_xor(sd, 4);
    if (oct == 0) {
      int ng = n0 + n;
      out_res[ng * 64 + d] = sr + b4[d];
      atomicAdd(&out_log[ng], logf(fabsf(sd) + 1e-8f));
    }
  }
}

extern "C" void kernel_launch(void* const* d_in, const int* in_sizes, int n_in,
                              void* d_out, int out_size, void* d_ws, size_t ws_size,
                              hipStream_t stream) {
  (void)in_sizes; (void)n_in; (void)out_size; (void)d_ws; (void)ws_size;
  const float* x  = (const float*)d_in[0];
  const float* W1 = (const float*)d_in[1];
  const float* b1 = (const float*)d_in[2];
  const float* W2 = (const float*)d_in[3];
  const float* b2 = (const float*)d_in[4];
  const float* W3 = (const float*)d_in[5];
  const float* b3 = (const float*)d_in[6];
  const float* W4 = (const float*)d_in[7];
  const float* b4 = (const float*)d_in[8];
  // d_in[9] = lags (==1, compile-time assumed)

  float* out_res = (float*)d_out;
  float* out_log = out_res + Nn * Dd;

  // log_abs_det accumulated via atomics over the 64 latent dims
  hipMemsetAsync(out_log, 0, Nn * sizeof(float), stream);

  dim3 grid(Nn / NT, Dd);
  np_prior_kernel<<<grid, 256, 0, stream>>>(x, W1, b1, W2, b2, W3, b3, W4, b4,
                                            out_res, out_log);
}

// Round 3
// 252.971 us; speedup vs baseline: 1.9393x; 1.9393x over previous
//
#include <hip/hip_runtime.h>
#include <hip/hip_bf16.h>
#include <math.h>

typedef _Float16 f16;
typedef _Float16 f16x8 __attribute__((ext_vector_type(8)));
typedef _Float16 f16x4 __attribute__((ext_vector_type(4)));
typedef _Float16 f16x2 __attribute__((ext_vector_type(2)));
typedef float f32x4 __attribute__((ext_vector_type(4)));

#define MFMA(a, b, c) __builtin_amdgcn_mfma_f32_16x16x32_f16((a), (b), (c), 0, 0, 0)

constexpr int Dd = 64;
constexpr int Hh = 128;
constexpr int Nn = 4096;
constexpr int NT = 32;
constexpr float SLP = 0.2f;
constexpr float INV2K = 1.0f / 2048.0f;

// Per-d f16 layout in d_ws (preprocessed, pre-swizzled, hi/lo split):
//   [0,8192)      W1 half0: hi 4096 | lo 4096   (compact K=64 swizzle)
//   [8192,16384)  W1 half1
//   [16384,49152) W2: h0 (hi 8192 | lo 8192), h1
//   [49152,81920) W3: h0, h1
constexpr int PD = 81920;  // f16 per d
constexpr size_t W1L_OFF = (size_t)Dd * PD * 2;  // bytes; then w1last f32[64][128]
constexpr size_t WS_NEEDED = W1L_OFF + (size_t)Dd * Hh * 4;

// XOR swizzle, [r][128] f16, 8-elem chunks, chunk ^= r&15 (2-way max = free)
__device__ __forceinline__ int swz(int r, int c) {
  return (r << 7) + ((((c >> 3) ^ (r & 15)) << 3) | (c & 7));
}
// Compact K=64 swizzle, [r][64] f16, chunk ^= r&7
__device__ __forceinline__ int swzK64(int r, int c) {
  return (r << 6) + (((((c >> 3) ^ r) & 7) << 3) | (c & 7));
}
// f32 overlay swizzle, [n][128] f32, 4-elem chunks, chunk ^= n&31
__device__ __forceinline__ int swzF(int n, int h) {
  return (n << 7) + ((((h >> 2) ^ n) & 31) << 2) + (h & 3);
}

struct HL { f16 h, l; };
__device__ __forceinline__ HL split(float v) {
  HL r;
  r.h = (f16)v;
  r.l = (f16)((v - (float)r.h) * 2048.0f);
  return r;
}

// Async contiguous global->LDS copy; nbytes multiple of 4096 (256 thr x 16B).
__device__ __forceinline__ void cp_lds_async(const void* g, void* l, int nbytes, int tid) {
  const int lane = tid & 63, wv = tid >> 6;
  for (int base = wv * 1024; base < nbytes; base += 4096) {
    __builtin_amdgcn_global_load_lds(
        (const __attribute__((address_space(1))) void*)((const char*)g + base + lane * 16),
        (__attribute__((address_space(3))) void*)((char*)l + base), 16, 0, 0);
  }
}

// ---------------- preprocess: split + pre-swizzle weights into d_ws ----------
__global__ __launch_bounds__(256)
void prep_kernel(const float* __restrict__ W1, const float* __restrict__ W2,
                 const float* __restrict__ W3, f16* __restrict__ wsf,
                 float* __restrict__ w1lg) {
  const int d = blockIdx.x, sec = blockIdx.y, tid = threadIdx.x;
  f16* out = wsf + (size_t)d * PD;
  if (sec == 0) {
    const float* W1d = W1 + d * Hh * 65;
    for (int ip = tid; ip < 4096; ip += 256) {  // pairs over 128x64
      int h = ip >> 5, k2 = (ip & 31) << 1;
      HL a = split(W1d[h * 65 + k2]);
      HL b = split(W1d[h * 65 + k2 + 1]);
      int o = (h >> 6) * 8192 + swzK64(h & 63, k2);
      *(f16x2*)&out[o] = f16x2{a.h, b.h};
      *(f16x2*)&out[o + 4096] = f16x2{a.l, b.l};
    }
    if (tid < 128) w1lg[d * Hh + tid] = W1d[tid * 65 + 64];
  } else {
    int w = (sec - 1) >> 1, hh = (sec - 1) & 1;  // w: 0=W2 1=W3
    const float* g = (w == 0 ? W2 : W3) + d * Hh * Hh + hh * 8192;
    f16* ob = out + 16384 + w * 32768 + hh * 16384;
    for (int ip = tid; ip < 4096; ip += 256) {  // pairs over 64x128
      int h = ip >> 6, k2 = (ip & 63) << 1;
      float2 v = *(const float2*)&g[h * 128 + k2];
      HL a = split(v.x), b = split(v.y);
      int o = swz(h, k2);
      *(f16x2*)&ob[o] = f16x2{a.h, b.h};
      *(f16x2*)&ob[o + 8192] = f16x2{a.l, b.l};
    }
  }
}

// ---------------- main fused kernel (fast path) ------------------------------
__device__ __forceinline__ void mid_mfma_half(
    const f16* AH, const f16* AL, const f16* DH, const f16* DL,
    const f16* WH, const f16* WL, int nt, int wq, int l15, int quad,
    f32x4* aP, f32x4* aS, f32x4* dP, f32x4* dS) {
#pragma unroll
  for (int kc = 0; kc < 4; kc++) {
    int ko = kc * 32 + quad * 8;
    int ra = nt * 16 + l15;
    f16x8 xh = *(const f16x8*)&AH[swz(ra, ko)];
    f16x8 xl = *(const f16x8*)&AL[swz(ra, ko)];
    f16x8 yh = *(const f16x8*)&DH[swz(ra, ko)];
    f16x8 yl = *(const f16x8*)&DL[swz(ra, ko)];
#pragma unroll
    for (int c2 = 0; c2 < 2; c2++) {
      int hr = (2 * wq + c2) * 16 + l15;
      f16x8 wh = *(const f16x8*)&WH[swz(hr, ko)];
      f16x8 wl = *(const f16x8*)&WL[swz(hr, ko)];
      aP[c2] = MFMA(wh, xh, aP[c2]);
      aS[c2] = MFMA(wl, xh, aS[c2]);
      aS[c2] = MFMA(wh, xl, aS[c2]);
      dP[c2] = MFMA(wh, yh, dP[c2]);
      dS[c2] = MFMA(wl, yh, dS[c2]);
      dS[c2] = MFMA(wh, yl, dS[c2]);
    }
  }
}

__global__ __launch_bounds__(256, 2)
void np_prior_fast(const float* __restrict__ x, const f16* __restrict__ wsw,
                   const float* __restrict__ w1lg,
                   const float* __restrict__ b1, const float* __restrict__ b2,
                   const float* __restrict__ b3, const float* __restrict__ W4,
                   const float* __restrict__ b4,
                   float* __restrict__ out_res, float* __restrict__ out_log) {
  __shared__ float4 smem[4096];  // 64 KB
  f16* AH = (f16*)smem;
  f16* AL = AH + NT * 128;
  f16* DH = AL + NT * 128;
  f16* DL = DH + NT * 128;
  f16* Wreg = (f16*)((char*)smem + 32768);   // 32 KB W staging
  float* A3F = (float*)smem;                 // f32 overlay (swzF)
  float* D3F = (float*)((char*)smem + 16384);

  const int tid = threadIdx.x, d = blockIdx.y, n0 = blockIdx.x * NT;
  const int lane = tid & 63, wv = tid >> 6, l15 = lane & 15, quad = lane >> 4;
  const int nt = wv & 1, wq = wv >> 1;

  const f16* wd = wsw + (size_t)d * PD;
  const float* w1l = w1lg + d * Hh;
  const float* b1d = b1 + d * Hh;
  const f32x4 zero = {0.f, 0.f, 0.f, 0.f};

  // W1 half0 in flight while we split-stage x
  cp_lds_async(wd, Wreg, 16384, tid);

  for (int i = tid; i < NT * 16; i += 256) {
    int n = i >> 4, k4 = (i & 15) << 2;
    int ng = n0 + n, bb = ng >> 8, tt = ng & 255;
    float4 v = *(const float4*)&x[(bb * 257 + tt) * 64 + k4];
    HL a = split(v.x), b = split(v.y), c = split(v.z), e = split(v.w);
    int o = swz(n, k4);
    *(f16x4*)&AH[o] = f16x4{a.h, b.h, c.h, e.h};
    *(f16x4*)&AL[o] = f16x4{a.l, b.l, c.l, e.l};
  }
  float xtv;
  {
    int ng = n0 + nt * 16 + l15, bb = ng >> 8, tt = ng & 255;
    xtv = x[(bb * 257 + tt + 1) * 64 + d];
  }
  __syncthreads();

  // ---- Layer 1 (K=64)
  f32x4 l1P[2][2], l1S[2][2];
  for (int hf = 0; hf < 2; hf++) {
    if (hf == 1) {
      __syncthreads();
      cp_lds_async(wd + 8192, Wreg, 16384, tid);
      __syncthreads();
    }
    l1P[hf][0] = zero; l1P[hf][1] = zero;
    l1S[hf][0] = zero; l1S[hf][1] = zero;
#pragma unroll
    for (int kc = 0; kc < 2; kc++) {
      int ko = kc * 32 + quad * 8;
      f16x8 xh = *(const f16x8*)&AH[swz(nt * 16 + l15, ko)];
      f16x8 xl = *(const f16x8*)&AL[swz(nt * 16 + l15, ko)];
#pragma unroll
      for (int c2 = 0; c2 < 2; c2++) {
        int hr = (2 * wq + c2) * 16 + l15;
        f16x8 wh = *(const f16x8*)&Wreg[swzK64(hr, ko)];
        f16x8 wl = *(const f16x8*)&Wreg[4096 + swzK64(hr, ko)];
        l1P[hf][c2] = MFMA(wh, xh, l1P[hf][c2]);
        l1S[hf][c2] = MFMA(wl, xh, l1S[hf][c2]);
        l1S[hf][c2] = MFMA(wh, xl, l1S[hf][c2]);
      }
    }
  }
  __syncthreads();
  cp_lds_async(wd + 16384, Wreg, 32768, tid);  // W2 h0, overlaps epilogue

  // ---- L1 epilogue: a1 = leaky(p1), d1 = s1 * W1[:,64]
  {
    int n = nt * 16 + l15;
#pragma unroll
    for (int hf = 0; hf < 2; hf++)
#pragma unroll
      for (int c2 = 0; c2 < 2; c2++) {
        int hb = hf * 64 + (2 * wq + c2) * 16 + quad * 4;
        float4 wv4 = *(const float4*)&w1l[hb];
        float4 bv4 = *(const float4*)&b1d[hb];
        f16x4 ah, al, dh, dl;
#pragma unroll
        for (int j = 0; j < 4; j++) {
          float w1j = (&wv4.x)[j];
          float p = l1P[hf][c2][j] + l1S[hf][c2][j] * INV2K + xtv * w1j + (&bv4.x)[j];
          float s = p > 0.f ? 1.f : SLP;
          HL av = split(p * s), dv = split(s * w1j);
          ah[j] = av.h; al[j] = av.l; dh[j] = dv.h; dl[j] = dv.l;
        }
        int o = swz(n, hb);
        *(f16x4*)&AH[o] = ah; *(f16x4*)&AL[o] = al;
        *(f16x4*)&DH[o] = dh; *(f16x4*)&DL[o] = dl;
      }
  }
  __syncthreads();

  // ---- Layer 2
  f32x4 aP[2][2], aS[2][2], dP[2][2], dS[2][2];
  for (int hf = 0; hf < 2; hf++) {
    if (hf == 1) {
      __syncthreads();
      cp_lds_async(wd + 32768, Wreg, 32768, tid);  // W2 h1
      __syncthreads();
    }
    aP[hf][0] = zero; aP[hf][1] = zero; aS[hf][0] = zero; aS[hf][1] = zero;
    dP[hf][0] = zero; dP[hf][1] = zero; dS[hf][0] = zero; dS[hf][1] = zero;
    mid_mfma_half(AH, AL, DH, DL, Wreg, Wreg + 8192, nt, wq, l15, quad,
                  aP[hf], aS[hf], dP[hf], dS[hf]);
  }
  __syncthreads();
  cp_lds_async(wd + 49152, Wreg, 32768, tid);  // W3 h0, overlaps epilogue

  // ---- L2 epilogue
  {
    const float* b2d = b2 + d * Hh;
    int n = nt * 16 + l15;
#pragma unroll
    for (int hf = 0; hf < 2; hf++)
#pragma unroll
      for (int c2 = 0; c2 < 2; c2++) {
        int hb = hf * 64 + (2 * wq + c2) * 16 + quad * 4;
        float4 bv4 = *(const float4*)&b2d[hb];
        f16x4 ah, al, dh, dl;
#pragma unroll
        for (int j = 0; j < 4; j++) {
          float p = aP[hf][c2][j] + aS[hf][c2][j] * INV2K + (&bv4.x)[j];
          float s = p > 0.f ? 1.f : SLP;
          float dd = s * (dP[hf][c2][j] + dS[hf][c2][j] * INV2K);
          HL av = split(p * s), dv = split(dd);
          ah[j] = av.h; al[j] = av.l; dh[j] = dv.h; dl[j] = dv.l;
        }
        int o = swz(n, hb);
        *(f16x4*)&AH[o] = ah; *(f16x4*)&AL[o] = al;
        *(f16x4*)&DH[o] = dh; *(f16x4*)&DL[o] = dl;
      }
  }
  __syncthreads();

  // ---- Layer 3
  for (int hf = 0; hf < 2; hf++) {
    if (hf == 1) {
      __syncthreads();
      cp_lds_async(wd + 65536, Wreg, 32768, tid);  // W3 h1
      __syncthreads();
    }
    aP[hf][0] = zero; aP[hf][1] = zero; aS[hf][0] = zero; aS[hf][1] = zero;
    dP[hf][0] = zero; dP[hf][1] = zero; dS[hf][0] = zero; dS[hf][1] = zero;
    mid_mfma_half(AH, AL, DH, DL, Wreg, Wreg + 8192, nt, wq, l15, quad,
                  aP[hf], aS[hf], dP[hf], dS[hf]);
  }
  __syncthreads();  // act reads done; f32 overlay becomes safe

  // ---- L3 epilogue -> swizzled f32 overlay
  {
    const float* b3d = b3 + d * Hh;
    int n = nt * 16 + l15;
#pragma unroll
    for (int hf = 0; hf < 2; hf++)
#pragma unroll
      for (int c2 = 0; c2 < 2; c2++) {
        int hb = hf * 64 + (2 * wq + c2) * 16 + quad * 4;
        float4 bv4 = *(const float4*)&b3d[hb];
        float4 pa, pd;
#pragma unroll
        for (int j = 0; j < 4; j++) {
          float p = aP[hf][c2][j] + aS[hf][c2][j] * INV2K + (&bv4.x)[j];
          float s = p > 0.f ? 1.f : SLP;
          (&pa.x)[j] = p * s;
          (&pd.x)[j] = s * (dP[hf][c2][j] + dS[hf][c2][j] * INV2K);
        }
        *(float4*)&A3F[swzF(n, hb)] = pa;
        *(float4*)&D3F[swzF(n, hb)] = pd;
      }
  }
  __syncthreads();

  // ---- Layer 4: fp32 VALU dot, 8 threads per sample
  {
    int n = tid >> 3, oct = tid & 7;
    const float* w4d = W4 + d * Hh;
    float sr = 0.f, sd = 0.f;
#pragma unroll
    for (int i = 0; i < 4; i++) {
      int c = oct * 16 + i * 4;
      float4 va = *(const float4*)&A3F[swzF(n, c)];
      float4 vd = *(const float4*)&D3F[swzF(n, c)];
      float4 w = *(const float4*)&w4d[c];
      sr += va.x * w.x + va.y * w.y + va.z * w.z + va.w * w.w;
      sd += vd.x * w.x + vd.y * w.y + vd.z * w.z + vd.w * w.w;
    }
    sr += __shfl_xor(sr, 1); sr += __shfl_xor(sr, 2); sr += __shfl_xor(sr, 4);
    sd += __shfl_xor(sd, 1); sd += __shfl_xor(sd, 2); sd += __shfl_xor(sd, 4);
    if (oct == 0) {
      int ng = n0 + n;
      out_res[ng * 64 + d] = sr + b4[d];
      atomicAdd(&out_log[ng], logf(fabsf(sd) + 1e-8f));
    }
  }
}

// ---------------- fallback (R2 kernel, used only if ws too small) ------------
__device__ __forceinline__ void stage_wf(f16* WH, f16* WL,
                                         const float* __restrict__ g, int tid) {
  for (int i = tid; i < 2048; i += 256) {
    int h = i >> 5, k4 = (i & 31) << 2;
    float4 v = ((const float4*)g)[i];
    HL a = split(v.x), b = split(v.y), c = split(v.z), e = split(v.w);
    int o = swz(h, k4);
    *(f16x4*)&WH[o] = f16x4{a.h, b.h, c.h, e.h};
    *(f16x4*)&WL[o] = f16x4{a.l, b.l, c.l, e.l};
  }
}

__global__ __launch_bounds__(256, 2)
void np_prior_fb(const float* __restrict__ x,
                 const float* __restrict__ W1, const float* __restrict__ b1,
                 const float* __restrict__ W2, const float* __restrict__ b2,
                 const float* __restrict__ W3, const float* __restrict__ b3,
                 const float* __restrict__ W4, const float* __restrict__ b4,
                 float* __restrict__ out_res, float* __restrict__ out_log) {
  __shared__ float4 smem[4096];
  f16* AH = (f16*)smem;
  f16* AL = AH + NT * 128;
  f16* DH = AL + NT * 128;
  f16* DL = DH + NT * 128;
  f16* WHp = (f16*)((char*)smem + 32768);
  f16* WLp = WHp + 64 * 128;
  float* A3F = (float*)smem;
  float* D3F = (float*)((char*)smem + 16384);

  const int tid = threadIdx.x, d = blockIdx.y, n0 = blockIdx.x * NT;
  const int lane = tid & 63, wv = tid >> 6, l15 = lane & 15, quad = lane >> 4;
  const int nt = wv & 1, wq = wv >> 1;

  const float* W1d = W1 + d * Hh * 65;
  const float* b1d = b1 + d * Hh;
  const f32x4 zero = {0.f, 0.f, 0.f, 0.f};

  for (int i = tid; i < NT * 16; i += 256) {
    int n = i >> 4, k4 = (i & 15) << 2;
    int ng = n0 + n, bb = ng >> 8, tt = ng & 255;
    float4 v = *(const float4*)&x[(bb * 257 + tt) * 64 + k4];
    HL a = split(v.x), b = split(v.y), c = split(v.z), e = split(v.w);
    int o = swz(n, k4);
    *(f16x4*)&AH[o] = f16x4{a.h, b.h, c.h, e.h};
    *(f16x4*)&AL[o] = f16x4{a.l, b.l, c.l, e.l};
  }
  float xtv;
  {
    int ng = n0 + nt * 16 + l15, bb = ng >> 8, tt = ng & 255;
    xtv = x[(bb * 257 + tt + 1) * 64 + d];
  }
  for (int i = tid; i < 64 * 64; i += 256) {
    int h = i >> 6, k = i & 63;
    HL s = split(W1d[h * 65 + k]);
    int o = swz(h, k);
    WHp[o] = s.h; WLp[o] = s.l;
  }
  __syncthreads();

  f32x4 l1P[2][2], l1S[2][2];
  for (int hf = 0; hf < 2; hf++) {
    if (hf == 1) {
      __syncthreads();
      for (int i = tid; i < 64 * 64; i += 256) {
        int h = i >> 6, k = i & 63;
        HL s = split(W1d[(64 + h) * 65 + k]);
        int o = swz(h, k);
        WHp[o] = s.h; WLp[o] = s.l;
      }
      __syncthreads();
    }
    l1P[hf][0] = zero; l1P[hf][1] = zero;
    l1S[hf][0] = zero; l1S[hf][1] = zero;
#pragma unroll
    for (int kc = 0; kc < 2; kc++) {
      int ko = kc * 32 + quad * 8;
      f16x8 xh = *(const f16x8*)&AH[swz(nt * 16 + l15, ko)];
      f16x8 xl = *(const f16x8*)&AL[swz(nt * 16 + l15, ko)];
#pragma unroll
      for (int c2 = 0; c2 < 2; c2++) {
        int hr = (2 * wq + c2) * 16 + l15;
        f16x8 wh = *(const f16x8*)&WHp[swz(hr, ko)];
        f16x8 wl = *(const f16x8*)&WLp[swz(hr, ko)];
        l1P[hf][c2] = MFMA(wh, xh, l1P[hf][c2]);
        l1S[hf][c2] = MFMA(wl, xh, l1S[hf][c2]);
        l1S[hf][c2] = MFMA(wh, xl, l1S[hf][c2]);
      }
    }
  }
  __syncthreads();

  {
    int n = nt * 16 + l15;
#pragma unroll
    for (int hf = 0; hf < 2; hf++)
#pragma unroll
      for (int c2 = 0; c2 < 2; c2++) {
        int hb = hf * 64 + (2 * wq + c2) * 16 + quad * 4;
        f16x4 ah, al, dh, dl;
#pragma unroll
        for (int j = 0; j < 4; j++) {
          int h = hb + j;
          float w1j = W1d[h * 65 + 64];
          float p = l1P[hf][c2][j] + l1S[hf][c2][j] * INV2K + xtv * w1j + b1d[h];
          float s = p > 0.f ? 1.f : SLP;
          HL av = split(p * s), dv = split(s * w1j);
          ah[j] = av.h; al[j] = av.l; dh[j] = dv.h; dl[j] = dv.l;
        }
        int o = swz(n, hb);
        *(f16x4*)&AH[o] = ah; *(f16x4*)&AL[o] = al;
        *(f16x4*)&DH[o] = dh; *(f16x4*)&DL[o] = dl;
      }
  }
  stage_wf(WHp, WLp, W2 + d * Hh * Hh, tid);
  __syncthreads();

  f32x4 aP[2][2], aS[2][2], dP[2][2], dS[2][2];
  for (int hf = 0; hf < 2; hf++) {
    if (hf == 1) {
      __syncthreads();
      stage_wf(WHp, WLp, W2 + d * Hh * Hh + 64 * 128, tid);
      __syncthreads();
    }
    aP[hf][0] = zero; aP[hf][1] = zero; aS[hf][0] = zero; aS[hf][1] = zero;
    dP[hf][0] = zero; dP[hf][1] = zero; dS[hf][0] = zero; dS[hf][1] = zero;
    mid_mfma_half(AH, AL, DH, DL, WHp, WLp, nt, wq, l15, quad,
                  aP[hf], aS[hf], dP[hf], dS[hf]);
  }
  __syncthreads();

  {
    const float* b2d = b2 + d * Hh;
    int n = nt * 16 + l15;
#pragma unroll
    for (int hf = 0; hf < 2; hf++)
#pragma unroll
      for (int c2 = 0; c2 < 2; c2++) {
        int hb = hf * 64 + (2 * wq + c2) * 16 + quad * 4;
        f16x4 ah, al, dh, dl;
#pragma unroll
        for (int j = 0; j < 4; j++) {
          int h = hb + j;
          float p = aP[hf][c2][j] + aS[hf][c2][j] * INV2K + b2d[h];
          float s = p > 0.f ? 1.f : SLP;
          float dd = s * (dP[hf][c2][j] + dS[hf][c2][j] * INV2K);
          HL av = split(p * s), dv = split(dd);
          ah[j] = av.h; al[j] = av.l; dh[j] = dv.h; dl[j] = dv.l;
        }
        int o = swz(n, hb);
        *(f16x4*)&AH[o] = ah; *(f16x4*)&AL[o] = al;
        *(f16x4*)&DH[o] = dh; *(f16x4*)&DL[o] = dl;
      }
  }
  stage_wf(WHp, WLp, W3 + d * Hh * Hh, tid);
  __syncthreads();

  for (int hf = 0; hf < 2; hf++) {
    if (hf == 1) {
      __syncthreads();
      stage_wf(WHp, WLp, W3 + d * Hh * Hh + 64 * 128, tid);
      __syncthreads();
    }
    aP[hf][0] = zero; aP[hf][1] = zero; aS[hf][0] = zero; aS[hf][1] = zero;
    dP[hf][0] = zero; dP[hf][1] = zero; dS[hf][0] = zero; dS[hf][1] = zero;
    mid_mfma_half(AH, AL, DH, DL, WHp, WLp, nt, wq, l15, quad,
                  aP[hf], aS[hf], dP[hf], dS[hf]);
  }
  __syncthreads();

  {
    const float* b3d = b3 + d * Hh;
    int n = nt * 16 + l15;
#pragma unroll
    for (int hf = 0; hf < 2; hf++)
#pragma unroll
      for (int c2 = 0; c2 < 2; c2++) {
        int hb = hf * 64 + (2 * wq + c2) * 16 + quad * 4;
        float4 pa, pd;
#pragma unroll
        for (int j = 0; j < 4; j++) {
          int h = hb + j;
          float p = aP[hf][c2][j] + aS[hf][c2][j] * INV2K + b3d[h];
          float s = p > 0.f ? 1.f : SLP;
          (&pa.x)[j] = p * s;
          (&pd.x)[j] = s * (dP[hf][c2][j] + dS[hf][c2][j] * INV2K);
        }
        *(float4*)&A3F[swzF(n, hb)] = pa;
        *(float4*)&D3F[swzF(n, hb)] = pd;
      }
  }
  __syncthreads();

  {
    int n = tid >> 3, oct = tid & 7;
    const float* w4d = W4 + d * Hh;
    float sr = 0.f, sd = 0.f;
#pragma unroll
    for (int i = 0; i < 4; i++) {
      int c = oct * 16 + i * 4;
      float4 va = *(const float4*)&A3F[swzF(n, c)];
      float4 vd = *(const float4*)&D3F[swzF(n, c)];
      float4 w = *(const float4*)&w4d[c];
      sr += va.x * w.x + va.y * w.y + va.z * w.z + va.w * w.w;
      sd += vd.x * w.x + vd.y * w.y + vd.z * w.z + vd.w * w.w;
    }
    sr += __shfl_xor(sr, 1); sr += __shfl_xor(sr, 2); sr += __shfl_xor(sr, 4);
    sd += __shfl_xor(sd, 1); sd += __shfl_xor(sd, 2); sd += __shfl_xor(sd, 4);
    if (oct == 0) {
      int ng = n0 + n;
      out_res[ng * 64 + d] = sr + b4[d];
      atomicAdd(&out_log[ng], logf(fabsf(sd) + 1e-8f));
    }
  }
}

extern "C" void kernel_launch(void* const* d_in, const int* in_sizes, int n_in,
                              void* d_out, int out_size, void* d_ws, size_t ws_size,
                              hipStream_t stream) {
  (void)in_sizes; (void)n_in; (void)out_size;
  const float* x  = (const float*)d_in[0];
  const float* W1 = (const float*)d_in[1];
  const float* b1 = (const float*)d_in[2];
  const float* W2 = (const float*)d_in[3];
  const float* b2 = (const float*)d_in[4];
  const float* W3 = (const float*)d_in[5];
  const float* b3 = (const float*)d_in[6];
  const float* W4 = (const float*)d_in[7];
  const float* b4 = (const float*)d_in[8];

  float* out_res = (float*)d_out;
  float* out_log = out_res + Nn * Dd;
  hipMemsetAsync(out_log, 0, Nn * sizeof(float), stream);

  dim3 grid(Nn / NT, Dd);
  if (ws_size >= WS_NEEDED) {
    f16* wsf = (f16*)d_ws;
    float* w1lg = (float*)((char*)d_ws + W1L_OFF);
    prep_kernel<<<dim3(Dd, 5), 256, 0, stream>>>(W1, W2, W3, wsf, w1lg);
    np_prior_fast<<<grid, 256, 0, stream>>>(x, wsf, w1lg, b1, b2, b3, W4, b4,
                                            out_res, out_log);
  } else {
    np_prior_fb<<<grid, 256, 0, stream>>>(x, W1, b1, W2, b2, W3, b3, W4, b4,
                                          out_res, out_log);
  }
}